// Round 4
// baseline (78.467 us; speedup 1.0000x reference)
//
#include <hip/hip_runtime.h>

#define BATCH 8
#define ROWS 1536
#define KCLS 32
#define NTOT (BATCH*ROWS)        // 12288
#define ELEMS (NTOT*16)          // 196608
#define SSTRIDE 3073             // padded prefix-sum stride per batch
#define BIGF 1.0e30f

// workspace layout (float offsets)
enum : int {
  WS_Z     = 0,                          // [8][1536][16]
  WS_X     = WS_Z + NTOT*16,             // [8][1536]
  WS_XS    = WS_X + NTOT,                // [8][1536]
  WS_S     = WS_XS + NTOT,               // [8][3073] padded
  WS_DESC  = WS_S + BATCH*SSTRIDE,       // [8][1536] int
  WS_ASCP  = WS_DESC + NTOT,             // [4][12288] int
  WS_DSCP  = WS_ASCP + 4*NTOT,           // [4][12288] int
  WS_GPART = WS_DSCP + 4*NTOT,           // [8][8][1536] (k8a) / [8][24][512] (cpart)
  WS_LOSSP = WS_GPART + BATCH*8*ROWS,    // [192]
};
#define WS_CPART WS_GPART   // disjoint lifetimes: cpart k1->k345, gpart k8a->k8b

// LDS weight layout (float offsets)
#define LW1  0
#define LB1  512
#define LW2  544
#define LB2  2592
#define LMW  2656
#define LMB  3680
#define LDW1 3696
#define LDB1 4208
#define LDW2 4240
#define LDB2 4752
#define LTOT 4768

// 16 FMAs: acc[0..15] += s * wsh[wbase .. wbase+15], via 4x ds_read_b128
#define FMA16(acc, wbase, s) do { \
    const float4* _wp = reinterpret_cast<const float4*>(&wsh[(wbase)]); \
    float4 _w0 = _wp[0], _w1 = _wp[1], _w2 = _wp[2], _w3 = _wp[3]; \
    (acc)[0]  = fmaf((s), _w0.x, (acc)[0]);  (acc)[1]  = fmaf((s), _w0.y, (acc)[1]); \
    (acc)[2]  = fmaf((s), _w0.z, (acc)[2]);  (acc)[3]  = fmaf((s), _w0.w, (acc)[3]); \
    (acc)[4]  = fmaf((s), _w1.x, (acc)[4]);  (acc)[5]  = fmaf((s), _w1.y, (acc)[5]); \
    (acc)[6]  = fmaf((s), _w1.z, (acc)[6]);  (acc)[7]  = fmaf((s), _w1.w, (acc)[7]); \
    (acc)[8]  = fmaf((s), _w2.x, (acc)[8]);  (acc)[9]  = fmaf((s), _w2.y, (acc)[9]); \
    (acc)[10] = fmaf((s), _w2.z, (acc)[10]); (acc)[11] = fmaf((s), _w2.w, (acc)[11]); \
    (acc)[12] = fmaf((s), _w3.x, (acc)[12]); (acc)[13] = fmaf((s), _w3.y, (acc)[13]); \
    (acc)[14] = fmaf((s), _w3.z, (acc)[14]); (acc)[15] = fmaf((s), _w3.w, (acc)[15]); \
  } while (0)

// ---- K1: autoencoder + z + loss partials + fused center partials ----
// Chunked accumulation keeps live registers ~80 floats -> no scratch spills.
__global__ __launch_bounds__(64, 2) void k1_ae(
    const float* __restrict__ table,
    const float* __restrict__ w1, const float* __restrict__ b1,
    const float* __restrict__ w2, const float* __restrict__ b2,
    const float* __restrict__ mw, const float* __restrict__ mb,
    const float* __restrict__ dw1, const float* __restrict__ db1,
    const float* __restrict__ dw2, const float* __restrict__ db2,
    const int* __restrict__ labels,
    float* __restrict__ ws)
{
  const int tid = threadIdx.x;
  const int blk = blockIdx.x;            // 0..191
  const int row = blk * 64 + tid;        // global row
  const int b   = blk / 24;              // batch
  const int ch  = blk % 24;              // 64-row chunk within batch

  __shared__ float wsh[LTOT];
  __shared__ float zsh[64 * 17];         // stride 17: bank-conflict-free
  __shared__ int   lbl[64];

  // stage weights (float4, coalesced)
  {
    float4* d4 = reinterpret_cast<float4*>(wsh);
#define CPY(off, src, nf4) \
    { const float4* p = reinterpret_cast<const float4*>(src); \
      for (int t = tid; t < (nf4); t += 64) d4[(off)/4 + t] = p[t]; }
    CPY(LW1,  w1,  128) CPY(LB1,  b1,  8)  CPY(LW2,  w2,  512)
    CPY(LB2,  b2,  16)  CPY(LMW,  mw,  256) CPY(LMB,  mb,  4)
    CPY(LDW1, dw1, 128) CPY(LDB1, db1, 8)  CPY(LDW2, dw2, 128)
    CPY(LDB2, db2, 4)
#undef CPY
    lbl[tid] = labels[ch * 64 + tid];
  }
  __syncthreads();

  float x[16];
  {
    const float4* tp = reinterpret_cast<const float4*>(table + row * 16);
    float4 a0 = tp[0], a1 = tp[1], a2 = tp[2], a3 = tp[3];
    x[0]=a0.x; x[1]=a0.y; x[2]=a0.z; x[3]=a0.w;
    x[4]=a1.x; x[5]=a1.y; x[6]=a1.z; x[7]=a1.w;
    x[8]=a2.x; x[9]=a2.y; x[10]=a2.z; x[11]=a2.w;
    x[12]=a3.x; x[13]=a3.y; x[14]=a3.z; x[15]=a3.w;
  }

  // ---- encoder layer 1: h1[32] ----
  float h1[32];
#pragma unroll
  for (int j = 0; j < 32; ++j) h1[j] = wsh[LB1 + j];
#pragma unroll 4
  for (int i = 0; i < 16; ++i) {
    const float xi = x[i];
    FMA16(&h1[0],  LW1 + i*32,      xi);
    FMA16(&h1[16], LW1 + i*32 + 16, xi);
  }
#pragma unroll
  for (int j = 0; j < 32; ++j) h1[j] = fmaxf(h1[j], 0.f);

  // ---- encoder layer 2 + mean head, h2 in 4 chunks of 16 ----
  float z[16];
#pragma unroll
  for (int j = 0; j < 16; ++j) z[j] = wsh[LMB + j];
#pragma unroll
  for (int c2 = 0; c2 < 4; ++c2) {
    float h2c[16];
#pragma unroll
    for (int j = 0; j < 16; ++j) h2c[j] = wsh[LB2 + c2*16 + j];
#pragma unroll 4
    for (int i = 0; i < 32; ++i) {
      FMA16(h2c, LW2 + i*64 + c2*16, h1[i]);
    }
#pragma unroll
    for (int j = 0; j < 16; ++j) h2c[j] = fmaxf(h2c[j], 0.f);
#pragma unroll 4
    for (int i2 = 0; i2 < 16; ++i2) {
      FMA16(z, LMW + (c2*16 + i2)*16, h2c[i2]);
    }
  }

  {
    float4* zp = reinterpret_cast<float4*>(ws + WS_Z + row * 16);
    zp[0] = make_float4(z[0], z[1], z[2], z[3]);
    zp[1] = make_float4(z[4], z[5], z[6], z[7]);
    zp[2] = make_float4(z[8], z[9], z[10], z[11]);
    zp[3] = make_float4(z[12], z[13], z[14], z[15]);
#pragma unroll
    for (int j = 0; j < 16; ++j) zsh[tid*17 + j] = z[j];
  }

  // ---- decoder: r1 in 2 chunks of 16, rec accumulated ----
  float rec[16];
#pragma unroll
  for (int j = 0; j < 16; ++j) rec[j] = wsh[LDB2 + j];
#pragma unroll
  for (int c1 = 0; c1 < 2; ++c1) {
    float r1c[16];
#pragma unroll
    for (int j = 0; j < 16; ++j) r1c[j] = wsh[LDB1 + c1*16 + j];
#pragma unroll 4
    for (int i = 0; i < 16; ++i) {
      FMA16(r1c, LDW1 + i*32 + c1*16, z[i]);
    }
#pragma unroll
    for (int j = 0; j < 16; ++j) r1c[j] = fmaxf(r1c[j], 0.f);
#pragma unroll 4
    for (int i2 = 0; i2 < 16; ++i2) {
      FMA16(rec, LDW2 + (c1*16 + i2)*16, r1c[i2]);
    }
  }

  float ls = 0.f;
#pragma unroll
  for (int j = 0; j < 16; ++j) {
    float d = fmaxf(rec[j], 0.f) - x[j];
    ls = fmaf(d, d, ls);
  }
  for (int off = 32; off > 0; off >>= 1) ls += __shfl_down(ls, off);
  if (tid == 0) ws[WS_LOSSP + blk] = ls;

  // fused center partials over this 64-row chunk
  __syncthreads();
  float acc[8] = {0.f,0.f,0.f,0.f,0.f,0.f,0.f,0.f};
  for (int rr = 0; rr < 64; ++rr) {
    const int lb = lbl[rr];
#pragma unroll
    for (int p = 0; p < 8; ++p) {
      const int idx = tid*8 + p;
      acc[p] += (lb == (idx >> 4)) ? zsh[rr*17 + (idx & 15)] : 0.f;
    }
  }
#pragma unroll
  for (int p = 0; p < 8; ++p)
    ws[WS_CPART + (b*24 + ch)*512 + tid*8 + p] = acc[p];
}

// ---- K345: centers finalize + loss + d2 + normalizations + scores + x ------
__global__ __launch_bounds__(256) void k345(const int* __restrict__ labels,
                                            float* __restrict__ ws,
                                            float* __restrict__ out)
{
  const int b = blockIdx.x;
  const int tid = threadIdx.x;
  __shared__ int cnt[KCLS];
  __shared__ float cent[512];
  __shared__ float rmn[256], rmx[256];
  __shared__ int lbl_l[ROWS];

  // loss reduction (all blocks compute, block 0 writes)
  rmn[tid] = (tid < 192) ? ws[WS_LOSSP + tid] : 0.f;
  if (tid < KCLS) cnt[tid] = 0;
  __syncthreads();
  for (int off = 128; off > 0; off >>= 1) {
    if (tid < off) rmn[tid] += rmn[tid + off];
    __syncthreads();
  }
  if (b == 0 && tid == 0) out[3*NTOT] = rmn[0] / (float)ELEMS;

#pragma unroll
  for (int c = 0; c < 6; ++c) {
    int lb = labels[c*256 + tid];
    lbl_l[c*256 + tid] = lb;
    atomicAdd(&cnt[lb], 1);
  }
  __syncthreads();
#pragma unroll
  for (int e = tid; e < 512; e += 256) {
    float s = 0.f;
#pragma unroll
    for (int c = 0; c < 24; ++c) s += ws[WS_CPART + (b*24 + c)*512 + e];
    const int cn = cnt[e >> 4] > 1 ? cnt[e >> 4] : 1;
    cent[e] = s / (float)cn;
  }
  __syncthreads();

  // d2 per row (6 rows/thread), block min/max
  float d2v[6];
  float tmn = 3.0e38f, tmx = -3.0e38f;
#pragma unroll
  for (int c = 0; c < 6; ++c) {
    const int r = c*256 + tid;
    const int lb = lbl_l[r];
    const float4* zp = reinterpret_cast<const float4*>(ws + WS_Z + (b*ROWS + r)*16);
    const float4* cp = reinterpret_cast<const float4*>(&cent[lb*16]);
    float s = 0.f;
#pragma unroll
    for (int q = 0; q < 4; ++q) {
      float4 zv = zp[q], cv = cp[q];
      float d0 = zv.x - cv.x, d1 = zv.y - cv.y, d2_ = zv.z - cv.z, d3 = zv.w - cv.w;
      s += d0*d0 + d1*d1 + d2_*d2_ + d3*d3;
    }
    d2v[c] = s / 16.f;
    tmn = fminf(tmn, d2v[c]); tmx = fmaxf(tmx, d2v[c]);
  }
  rmn[tid] = tmn; rmx[tid] = tmx;
  __syncthreads();
  for (int off = 128; off > 0; off >>= 1) {
    if (tid < off) {
      rmn[tid] = fminf(rmn[tid], rmn[tid + off]);
      rmx[tid] = fmaxf(rmx[tid], rmx[tid + off]);
    }
    __syncthreads();
  }
  const float mn = rmn[0], mx = rmx[0];
  __syncthreads();

  float sv[6];
  tmn = 3.0e38f; tmx = -3.0e38f;
#pragma unroll
  for (int c = 0; c < 6; ++c) {
    const int r = c*256 + tid;
    float sc = (d2v[c] - mn) / (mx - mn) + (float)lbl_l[r];
    sv[c] = sc;
    out[2*NTOT + b*ROWS + r] = sc;
    tmn = fminf(tmn, sc); tmx = fmaxf(tmx, sc);
  }
  rmn[tid] = tmn; rmx[tid] = tmx;
  __syncthreads();
  for (int off = 128; off > 0; off >>= 1) {
    if (tid < off) {
      rmn[tid] = fminf(rmn[tid], rmn[tid + off]);
      rmx[tid] = fmaxf(rmx[tid], rmx[tid + off]);
    }
    __syncthreads();
  }
  const float smn = rmn[0], smx = rmx[0];
#pragma unroll
  for (int c = 0; c < 6; ++c) {
    const int r = c*256 + tid;
    float scl = (sv[c] - smn) / (smx - smn) * 8.0f;
    ws[WS_X + b*ROWS + r] = scl / 0.01f;
  }
}

// ---------------- K6: partial stable rank counts (192 blocks) ----------------
__global__ __launch_bounds__(256) void k6_count(float* __restrict__ ws,
                                                const float* __restrict__ out)
{
  const int bi = blockIdx.x;
  const int jb = bi & 3, rb = (bi >> 2) % 6, b = bi / 24;
  const int tid = threadIdx.x;
  __shared__ float4 sld[96], xld[96];
  {
    float* sf = reinterpret_cast<float*>(sld);
    float* xf = reinterpret_cast<float*>(xld);
    const int base = b*ROWS + jb*384;
    sf[tid] = out[2*NTOT + base + tid];
    xf[tid] = ws[WS_X + base + tid];
    if (tid < 128) {
      sf[256 + tid] = out[2*NTOT + base + 256 + tid];
      xf[256 + tid] = ws[WS_X + base + 256 + tid];
    }
  }
  __syncthreads();
  const int r = rb*256 + tid;
  const float si = out[2*NTOT + b*ROWS + r];
  const float xi = ws[WS_X + b*ROWS + r];
  int asc = 0, dsc = 0;
  const int j0 = jb*384;
#pragma unroll 4
  for (int kk = 0; kk < 96; ++kk) {
    const float4 s4 = sld[kk];
    const float4 x4 = xld[kk];
    const int j = j0 + kk*4;
    asc += (s4.x < si || (s4.x == si && j   < r)) ? 1 : 0;
    asc += (s4.y < si || (s4.y == si && j+1 < r)) ? 1 : 0;
    asc += (s4.z < si || (s4.z == si && j+2 < r)) ? 1 : 0;
    asc += (s4.w < si || (s4.w == si && j+3 < r)) ? 1 : 0;
    dsc += (x4.x > xi || (x4.x == xi && j   < r)) ? 1 : 0;
    dsc += (x4.y > xi || (x4.y == xi && j+1 < r)) ? 1 : 0;
    dsc += (x4.z > xi || (x4.z == xi && j+2 < r)) ? 1 : 0;
    dsc += (x4.w > xi || (x4.w == xi && j+3 < r)) ? 1 : 0;
  }
  int* wsi = reinterpret_cast<int*>(ws);
  wsi[WS_ASCP + jb*NTOT + b*ROWS + r] = asc;
  wsi[WS_DSCP + jb*NTOT + b*ROWS + r] = dsc;
}

// ------- K67: finalize counts -> rank_idx, scatter xs, prefix-sum S ---------
__global__ __launch_bounds__(256) void k67(const int* __restrict__ bsp,
                                           float* __restrict__ ws,
                                           float* __restrict__ out)
{
  const int b = blockIdx.x, tid = threadIdx.x;
  __shared__ float xs_l[ROWS];
  __shared__ float ts[256];
  const int* wsi = reinterpret_cast<const int*>(ws);
  int* wsw = reinterpret_cast<int*>(ws);
  const int BS = *bsp;
#pragma unroll
  for (int c = 0; c < 6; ++c) {
    const int r = c*256 + tid;
    const int idx = b*ROWS + r;
    int asc = 0, dsc = 0;
#pragma unroll
    for (int jb = 0; jb < 4; ++jb) {
      asc += wsi[WS_ASCP + jb*NTOT + idx];
      dsc += wsi[WS_DSCP + jb*NTOT + idx];
    }
    out[NTOT + idx] = (float)(asc / BS + 1);
    wsw[WS_DESC + idx] = dsc;
    xs_l[dsc] = ws[WS_X + idx];
  }
  __syncthreads();
  const int base = tid * 6;
  float y[6], sum = 0.f;
#pragma unroll
  for (int u = 0; u < 6; ++u) {
    ws[WS_XS + b*ROWS + base + u] = xs_l[base + u];
    y[u] = (float)(ROWS - (base + u)) - xs_l[base + u];
    sum += y[u];
  }
  ts[tid] = sum;
  __syncthreads();
  for (int off = 1; off < 256; off <<= 1) {
    float v = ts[tid];
    if (tid >= off) v += ts[tid - off];
    __syncthreads();
    ts[tid] = v;
    __syncthreads();
  }
  float run = tid ? ts[tid - 1] : 0.f;
  float* S = ws + WS_S + b*SSTRIDE;
#pragma unroll
  for (int u = 0; u < 6; ++u) { S[base + u] = run; run += y[u]; }
  if (tid == 255) S[ROWS] = run;
#pragma unroll
  for (int u = 0; u < 6; ++u) S[ROWS + 1 + tid*6 + u] = BIGF;
}

// ---------------- K8a: chunk-partial minima of segment averages --------------
__global__ __launch_bounds__(256) void k8a(float* __restrict__ ws)
{
  const int bi = blockIdx.x;
  const int c = bi & 7, ib = (bi >> 3) % 6, b = bi / 48;
  const int tid = threadIdx.x;
  __shared__ float Sseg[448];
  __shared__ float invl[192];
  const float* S = ws + WS_S + b*SSTRIDE;
  const int ibase = ib*256;
  const int segbase = ibase + c*192 + 1;
  Sseg[tid] = S[segbase + tid];
  if (tid < 192) {
    Sseg[256 + tid] = S[segbase + 256 + tid];
    invl[tid] = 1.0f / (float)(c*192 + tid + 1);
  }
  __syncthreads();
  const int i = ibase + tid;
  const float Si = S[i];
  float gm = 3.0e38f;
#pragma unroll 8
  for (int k = 0; k < 192; ++k)
    gm = fminf(gm, (Sseg[tid + k] - Si) * invl[k]);
  ws[WS_GPART + (b*8 + c)*ROWS + i] = gm;
}

// --------- K8b: reduce partials, prefix-max (isotonic), final ranks ----------
__global__ __launch_bounds__(768) void k8b(float* __restrict__ ws,
                                           float* __restrict__ out)
{
  const int b = blockIdx.x, tid = threadIdx.x;
  __shared__ float g[ROWS];
  __shared__ float pm[768];
  for (int t = tid; t < ROWS; t += 768) {
    float gm = 3.0e38f;
#pragma unroll
    for (int c = 0; c < 8; ++c)
      gm = fminf(gm, ws[WS_GPART + (b*8 + c)*ROWS + t]);
    g[t] = gm;
  }
  __syncthreads();
  const float a = g[2*tid], cc = g[2*tid + 1];
  pm[tid] = fmaxf(a, cc);
  __syncthreads();
  for (int off = 1; off < 768; off <<= 1) {
    float v = pm[tid];
    if (tid >= off) v = fmaxf(v, pm[tid - off]);
    __syncthreads();
    pm[tid] = v;
    __syncthreads();
  }
  const float excl = tid ? pm[tid - 1] : -3.0e38f;
  const float i0 = fmaxf(excl, a);
  const float i1 = fmaxf(i0, cc);
  g[2*tid] = i0; g[2*tid + 1] = i1;
  __syncthreads();
  const float* xs = ws + WS_XS + b*ROWS;
  const int* desc = reinterpret_cast<const int*>(ws) + WS_DESC + b*ROWS;
  for (int t = tid; t < ROWS; t += 768) {
    const int dr = desc[t];
    out[b*ROWS + t] = xs[dr] + g[dr];
  }
}

extern "C" void kernel_launch(void* const* d_in, const int* in_sizes, int n_in,
                              void* d_out, int out_size, void* d_ws, size_t ws_size,
                              hipStream_t stream) {
  const float* table = (const float*)d_in[0];
  const float* w1  = (const float*)d_in[1];
  const float* b1  = (const float*)d_in[2];
  const float* w2  = (const float*)d_in[3];
  const float* b2  = (const float*)d_in[4];
  const float* mw  = (const float*)d_in[5];
  const float* mb  = (const float*)d_in[6];
  const float* dw1 = (const float*)d_in[7];
  const float* db1 = (const float*)d_in[8];
  const float* dw2 = (const float*)d_in[9];
  const float* db2 = (const float*)d_in[10];
  const int* labels = (const int*)d_in[11];
  const int* bsp    = (const int*)d_in[12];
  float* out = (float*)d_out;
  float* ws  = (float*)d_ws;

  k1_ae<<<192, 64, 0, stream>>>(table, w1, b1, w2, b2, mw, mb, dw1, db1, dw2, db2, labels, ws);
  k345<<<8, 256, 0, stream>>>(labels, ws, out);
  k6_count<<<192, 256, 0, stream>>>(ws, out);
  k67<<<8, 256, 0, stream>>>(bsp, ws, out);
  k8a<<<384, 256, 0, stream>>>(ws);
  k8b<<<8, 768, 0, stream>>>(ws, out);
}